// Round 12
// baseline (139.736 us; speedup 1.0000x reference)
//
#include <hip/hip_runtime.h>
#include <cmath>

// CustomRankingLoss: greedy ERR/MMR selection, fused cooperative kernel.
// R12 = R11 (two-hop leader topology, 137.2us) + E_j ROW STAGING IN LDS:
//   per round, 128 threads load the selected 2KB row ONCE per block
//   (coalesced float4) into LDS; all 16 waves read it from LDS instead of
//   4096 redundant wave-reads of the same 16 global cache lines per round
//   (LLC hot-line serialization + publish-skew amplification).
// Raw row values identical -> all norms/dots bit-identical to R10/R11.
// Inputs: predictions[N], (unused x4), explanation_embeddings[N*D], k.
// Output: single float32 scalar. Hard-wired: N=32768, D=512, k<=16.

#define DECAYF 0.85f
#define LAMF   0.5f
#define EPSF   1e-12f

constexpr int D    = 512;
constexpr int KMAX = 16;
constexpr int NBLK = 256;   // 1 block per CU
constexpr int TPB  = 1024;  // 16 waves
constexpr int NW   = TPB / 64;   // 16
constexpr int RPW  = 8;          // rows per wave
constexpr int RPB  = NW * RPW;   // 128 rows per block
constexpr int BREP = 8;          // bcast replicas
constexpr int BSTR = 16;         // replica stride in u64 (128B)

using u32 = unsigned int;
using u64 = unsigned long long;

__device__ inline float wsum(float v) {
#pragma unroll
    for (int o = 32; o > 0; o >>= 1) v += __shfl_xor(v, o);
    return v;
}
__device__ inline float wmaxf(float v) {
#pragma unroll
    for (int o = 32; o > 0; o >>= 1) v = fmaxf(v, __shfl_xor(v, o));
    return v;
}
__device__ inline u64 wmax64(u64 v) {
#pragma unroll
    for (int o = 32; o > 0; o >>= 1) {
        u64 w = __shfl_xor(v, o);
        v = (w > v) ? w : v;
    }
    return v;
}
// order-preserving float -> u32 (monotone, handles -inf)
__device__ inline u32 fkey(float f) {
    u32 u = __float_as_uint(f);
    return (u & 0x80000000u) ? ~u : (u | 0x80000000u);
}
__device__ inline u64 aload(const u64* p) {
    return __hip_atomic_load(p, __ATOMIC_RELAXED, __HIP_MEMORY_SCOPE_AGENT);
}
__device__ inline u64 poll_sleep(const u64* p) {      // prologue only
    u64 v = aload(p);
    while (v == 0ull) { __builtin_amdgcn_s_sleep(1); v = aload(p); }
    return v;
}
__device__ inline u64 poll_tight(const u64* p) {      // round-loop polls
    u64 v = aload(p);
    while (v == 0ull) v = aload(p);
    return v;
}
__device__ inline void publish(u64* p, u64 v) {
    __hip_atomic_store(p, v, __ATOMIC_RELAXED, __HIP_MEMORY_SCOPE_AGENT);
}

__global__ __launch_bounds__(TPB, 4) void fused_kernel(
        const float* __restrict__ pred,
        const float* __restrict__ E,
        const int*   __restrict__ kptr,
        float* __restrict__ out,
        u64*   __restrict__ sm,      // [NBLK] packed (m_b, s_b)
        u64*   __restrict__ part,    // [KMAX][NBLK] argmax partials
        u64*   __restrict__ bcast) { // [KMAX][BREP*BSTR] replicated results
    const int b = blockIdx.x, tid = threadIdx.x;
    const int wv = tid >> 6, lane = tid & 63;

    __shared__ float pred_s[RPB];
    __shared__ float row_s[D];       // staged selected row (2KB)
    __shared__ u64   scan_s[NBLK];   // softmax combine staging (once)
    __shared__ u64   wkey_s[NW];
    __shared__ float m_s, S_s;
    __shared__ int   j_s;
    __shared__ int   sel_s[KMAX];
    __shared__ float invsel_s[KMAX];
    __shared__ float rmax_s[KMAX];

    int kk = kptr[0];
    if (kk > KMAX) kk = KMAX;
    if (kk < 0) kk = 0;

    // ---- Phase A: publish per-block softmax partials (needs only pred) ----
    if (tid < RPB) pred_s[tid] = pred[b * RPB + tid];
    __syncthreads();
    if (wv == 0) {
        float p0 = pred_s[lane], p1 = pred_s[lane + 64];
        float mb = wmaxf(fmaxf(p0, p1));
        float sb = wsum(expf(p0 - mb) + expf(p1 - mb));   // sb >= 1 -> bits != 0
        if (lane == 0)
            publish(&sm[b], ((u64)__float_as_uint(mb) << 32) | __float_as_uint(sb));
    }
    asm volatile("" ::: "memory");   // keep the publish before the E stream

    // ---- Phase B: stream E rows into registers + normalize (hides A) ----
    const int row0 = b * RPB + wv * RPW;
    float r[RPW][8];
#pragma unroll
    for (int rr = 0; rr < RPW; ++rr) {
        const float4* p = (const float4*)(E + (size_t)(row0 + rr) * D) + 2 * lane;
        float4 a0 = p[0], a1 = p[1];
        r[rr][0] = a0.x; r[rr][1] = a0.y; r[rr][2] = a0.z; r[rr][3] = a0.w;
        r[rr][4] = a1.x; r[rr][5] = a1.y; r[rr][6] = a1.z; r[rr][7] = a1.w;
        float ss = 0.f;
#pragma unroll
        for (int e = 0; e < 8; ++e) ss += r[rr][e] * r[rr][e];
        ss = wsum(ss);
        float inv = 1.f / (sqrtf(ss) + EPSF);
#pragma unroll
        for (int e = 0; e < 8; ++e) r[rr][e] *= inv;
        asm volatile("" : "+v"(r[rr][0]), "+v"(r[rr][1]), "+v"(r[rr][2]), "+v"(r[rr][3]),
                          "+v"(r[rr][4]), "+v"(r[rr][5]), "+v"(r[rr][6]), "+v"(r[rr][7]));
    }

    // ---- Phase C: combine softmax partials (slots long-visible by now) ----
    if (tid < NBLK) scan_s[tid] = poll_sleep(&sm[tid]);
    __syncthreads();
    if (wv == 0) {
        u64 v0 = scan_s[lane], v1 = scan_s[lane + 64],
            v2 = scan_s[lane + 128], v3 = scan_s[lane + 192];
        float m0 = __uint_as_float((u32)(v0 >> 32)), m1 = __uint_as_float((u32)(v1 >> 32));
        float m2 = __uint_as_float((u32)(v2 >> 32)), m3 = __uint_as_float((u32)(v3 >> 32));
        float M = wmaxf(fmaxf(fmaxf(m0, m1), fmaxf(m2, m3)));   // wave-uniform
        float acc = __uint_as_float((u32)(v0 & 0xFFFFFFFFull)) * expf(m0 - M)
                  + __uint_as_float((u32)(v1 & 0xFFFFFFFFull)) * expf(m1 - M)
                  + __uint_as_float((u32)(v2 & 0xFFFFFFFFull)) * expf(m2 - M)
                  + __uint_as_float((u32)(v3 & 0xFFFFFFFFull)) * expf(m3 - M);
        acc = wsum(acc);
        if (lane == 0) { m_s = M; S_s = acc; }
    }
    __syncthreads();
    const float M    = m_s;
    const float Sinv = 1.f / S_s;

    // per-wave private state (wave-uniform, registers). drel = decay^t * rel.
    float drel_r[RPW], msim_r[RPW];
#pragma unroll
    for (int rr = 0; rr < RPW; ++rr) {
        drel_r[rr] = expf(pred_s[wv * RPW + rr] - M) * Sinv;
        msim_r[rr] = 0.f;
    }

    // ---- greedy selection: two-hop + LDS row staging, 3 barriers/round ----
    int j = -1;
    for (int t = 0; t < KMAX; ++t) {
        if (t >= kk) break;                       // uniform across grid
        if (t > 0) {
            // stage row j into LDS once per block (coalesced, 2KB)
            if (tid < D / 4)
                ((float4*)row_s)[tid] = ((const float4*)(E + (size_t)j * D))[tid];
            __syncthreads();                                   // B0
            // per-lane 8 elems from LDS (raw values identical to global read)
            float bj[8];
#pragma unroll
            for (int e = 0; e < 8; ++e) bj[e] = row_s[lane * 8 + e];
            float ss = 0.f;
#pragma unroll
            for (int e = 0; e < 8; ++e) ss += bj[e] * bj[e];
            ss = wsum(ss);
            const float js = 1.f / (sqrtf(ss) + EPSF);
#pragma unroll
            for (int e = 0; e < 8; ++e) bj[e] *= js;
#pragma unroll
            for (int rr = 0; rr < RPW; ++rr) {
                float d = 0.f;
#pragma unroll
                for (int e = 0; e < 8; ++e) d += r[rr][e] * bj[e];
                d = wsum(d);
                msim_r[rr] = (row0 + rr == j) ? INFINITY
                                              : fmaxf(msim_r[rr], d);
            }
        }
        // wave-local best key (values wave-uniform)
        u64 best = 0ull;
#pragma unroll
        for (int rr = 0; rr < RPW; ++rr) {
            const float sc = drel_r[rr] - LAMF * msim_r[rr];
            const u64 key = ((u64)fkey(sc) << 32) | (u32)~(u32)(row0 + rr);
            best = (key > best) ? key : best;
        }
#pragma unroll
        for (int rr = 0; rr < RPW; ++rr) drel_r[rr] *= DECAYF;  // decay^(t+1)
        if (lane == 0) wkey_s[wv] = best;
        __syncthreads();                                       // B1
        if (wv == 0) {
            // block partial -> dense slot
            u64 v = (lane < NW) ? wkey_s[lane] : 0ull;
            v = wmax64(v);
            u64* base = part + (size_t)t * NBLK;
            if (lane == 0) publish(&base[b], v);
            u64* bc = bcast + (size_t)t * BREP * BSTR;
            if (b == 0) {
                // leader: interleaved non-blocking tight poll, 4 slots/lane
                u64 a0 = 0, a1 = 0, a2 = 0, a3 = 0;
                for (;;) {
                    if (a0 == 0ull) a0 = aload(&base[lane]);
                    if (a1 == 0ull) a1 = aload(&base[lane + 64]);
                    if (a2 == 0ull) a2 = aload(&base[lane + 128]);
                    if (a3 == 0ull) a3 = aload(&base[lane + 192]);
                    if (a0 && a1 && a2 && a3) break;
                }
                u64 m = (a1 > a0) ? a1 : a0;
                m = (a2 > m) ? a2 : m;
                m = (a3 > m) ? a3 : m;
                m = wmax64(m);                     // max in ALL lanes
                if (lane < BREP) publish(&bc[lane * BSTR], m);  // 8 replicas
            }
            if (lane == 0) {
                const u64 m = poll_tight(&bc[(b >> 5) * BSTR]);
                const int jj = (int)~(u32)(m & 0xFFFFFFFFull);
                j_s = jj;
                sel_s[t] = jj;
            }
        }
        __syncthreads();                                       // B2
        j = j_s;
    }

    // ---- epilogue (block 0 only) ----
    if (b == 0) {
        for (int ii = wv; ii < kk; ii += NW) {
            const int si = sel_s[ii];
            const float4* pa = (const float4*)(E + (size_t)si * D) + 2 * lane;
            float4 a0 = pa[0], a1 = pa[1];
            float ss = a0.x*a0.x + a0.y*a0.y + a0.z*a0.z + a0.w*a0.w
                     + a1.x*a1.x + a1.y*a1.y + a1.z*a1.z + a1.w*a1.w;
            ss = wsum(ss);
            if (lane == 0) invsel_s[ii] = 1.f / (sqrtf(ss) + EPSF);
        }
        __syncthreads();
        for (int ii = wv; ii < kk; ii += NW) {
            const int si = sel_s[ii];
            const float4* pa = (const float4*)(E + (size_t)si * D) + 2 * lane;
            float4 a0 = pa[0], a1 = pa[1];
            const float ia = invsel_s[ii];
            float av[8] = {a0.x * ia, a0.y * ia, a0.z * ia, a0.w * ia,
                           a1.x * ia, a1.y * ia, a1.z * ia, a1.w * ia};
            float m = -INFINITY;
            for (int jj = 0; jj < kk; ++jj) {
                const float4* pb = (const float4*)(E + (size_t)sel_s[jj] * D) + 2 * lane;
                float4 c0 = pb[0], c1 = pb[1];
                float d = av[0]*c0.x + av[1]*c0.y + av[2]*c0.z + av[3]*c0.w
                        + av[4]*c1.x + av[5]*c1.y + av[6]*c1.z + av[7]*c1.w;
                d = wsum(d);
                m = fmaxf(m, d * invsel_s[jj]);
            }
            if (lane == 0) rmax_s[ii] = m;
        }
        __syncthreads();
        if (tid == 0) {
            float es = 0.f, mm = 0.f;
            for (int t = 0; t < kk; ++t) {
                es += powf(DECAYF, (float)t) * expf(pred[sel_s[t]] - M) * Sinv;
                mm += rmax_s[t];
            }
            out[0] = -es - LAMF * mm;
        }
    }
}

extern "C" void kernel_launch(void* const* d_in, const int* in_sizes, int n_in,
                              void* d_out, int out_size, void* d_ws, size_t ws_size,
                              hipStream_t stream) {
    const float* pred = (const float*)d_in[0];
    const float* E    = (const float*)d_in[5];
    const int*   kptr = (const int*)d_in[6];
    float* out        = (float*)d_out;

    // workspace: sm[256] + part[16][256] + bcast[16][8*16], u64.
    // Zeroed each launch so poll sentinels (0) are fresh per graph replay.
    u64* sm    = (u64*)d_ws;
    u64* part  = sm + NBLK;
    u64* bcast = part + (size_t)KMAX * NBLK;
    const size_t tot = NBLK + (size_t)KMAX * NBLK + (size_t)KMAX * BREP * BSTR;
    hipMemsetAsync(d_ws, 0, tot * sizeof(u64), stream);

    void* args[] = {(void*)&pred, (void*)&E, (void*)&kptr, (void*)&out,
                    (void*)&sm, (void*)&part, (void*)&bcast};
    hipLaunchCooperativeKernel((const void*)fused_kernel,
                               dim3(NBLK), dim3(TPB), args, 0, stream);
}

// Round 13
// 136.700 us; speedup vs baseline: 1.0222x; 1.0222x over previous
//
#include <hip/hip_runtime.h>
#include <cmath>

// CustomRankingLoss: greedy ERR/MMR selection, fused cooperative kernel.
// R13 = R11 (two-hop leader topology, 137.2us; R12 LDS-staging reverted) +
// ROUND-0 PRE-PUBLISH: softmax is order-preserving, so argmax(rel) ==
// argmax(pred). Each block publishes its round-0 partial key (raw pred bits)
// in Phase A, in parallel with the softmax partial and BEFORE the E-stream.
// Round 0's communication then fully hides under the ~12us stream; the
// selection loop's t=0 is just {gather-visible-slots + bcast + detect}.
// Inputs: predictions[N], (unused x4), explanation_embeddings[N*D], k.
// Output: single float32 scalar. Hard-wired: N=32768, D=512, k<=16.

#define DECAYF 0.85f
#define LAMF   0.5f
#define EPSF   1e-12f

constexpr int D    = 512;
constexpr int KMAX = 16;
constexpr int NBLK = 256;   // 1 block per CU
constexpr int TPB  = 1024;  // 16 waves
constexpr int NW   = TPB / 64;   // 16
constexpr int RPW  = 8;          // rows per wave
constexpr int RPB  = NW * RPW;   // 128 rows per block
constexpr int BREP = 8;          // bcast replicas
constexpr int BSTR = 16;         // replica stride in u64 (128B)

using u32 = unsigned int;
using u64 = unsigned long long;

__device__ inline float wsum(float v) {
#pragma unroll
    for (int o = 32; o > 0; o >>= 1) v += __shfl_xor(v, o);
    return v;
}
__device__ inline float wmaxf(float v) {
#pragma unroll
    for (int o = 32; o > 0; o >>= 1) v = fmaxf(v, __shfl_xor(v, o));
    return v;
}
__device__ inline u64 wmax64(u64 v) {
#pragma unroll
    for (int o = 32; o > 0; o >>= 1) {
        u64 w = __shfl_xor(v, o);
        v = (w > v) ? w : v;
    }
    return v;
}
// order-preserving float -> u32 (monotone, handles -inf)
__device__ inline u32 fkey(float f) {
    u32 u = __float_as_uint(f);
    return (u & 0x80000000u) ? ~u : (u | 0x80000000u);
}
__device__ inline u64 aload(const u64* p) {
    return __hip_atomic_load(p, __ATOMIC_RELAXED, __HIP_MEMORY_SCOPE_AGENT);
}
__device__ inline u64 poll_sleep(const u64* p) {      // prologue only
    u64 v = aload(p);
    while (v == 0ull) { __builtin_amdgcn_s_sleep(1); v = aload(p); }
    return v;
}
__device__ inline u64 poll_tight(const u64* p) {      // round-loop polls
    u64 v = aload(p);
    while (v == 0ull) v = aload(p);
    return v;
}
__device__ inline void publish(u64* p, u64 v) {
    __hip_atomic_store(p, v, __ATOMIC_RELAXED, __HIP_MEMORY_SCOPE_AGENT);
}

__global__ __launch_bounds__(TPB, 4) void fused_kernel(
        const float* __restrict__ pred,
        const float* __restrict__ E,
        const int*   __restrict__ kptr,
        float* __restrict__ out,
        u64*   __restrict__ sm,      // [NBLK] packed (m_b, s_b)
        u64*   __restrict__ part,    // [KMAX][NBLK] argmax partials
        u64*   __restrict__ bcast) { // [KMAX][BREP*BSTR] replicated results
    const int b = blockIdx.x, tid = threadIdx.x;
    const int wv = tid >> 6, lane = tid & 63;

    __shared__ float pred_s[RPB];
    __shared__ u64   scan_s[NBLK];   // softmax combine staging (once)
    __shared__ u64   wkey_s[NW];
    __shared__ float m_s, S_s;
    __shared__ int   j_s;
    __shared__ int   sel_s[KMAX];
    __shared__ float invsel_s[KMAX];
    __shared__ float rmax_s[KMAX];

    int kk = kptr[0];
    if (kk > KMAX) kk = KMAX;
    if (kk < 0) kk = 0;

    // ---- Phase A: publish softmax partial AND round-0 argmax partial ----
    if (tid < RPB) pred_s[tid] = pred[b * RPB + tid];
    __syncthreads();
    if (wv == 0) {
        float p0 = pred_s[lane], p1 = pred_s[lane + 64];
        float mb = wmaxf(fmaxf(p0, p1));
        float sb = wsum(expf(p0 - mb) + expf(p1 - mb));   // sb >= 1 -> bits != 0
        if (lane == 0)
            publish(&sm[b], ((u64)__float_as_uint(mb) << 32) | __float_as_uint(sb));
    } else if (wv == 1 && kk > 0) {
        // round-0 partial: argmax(rel) == argmax(pred) (softmax monotone)
        float p0 = pred_s[lane], p1 = pred_s[lane + 64];
        u64 k0 = ((u64)fkey(p0) << 32) | (u32)~(u32)(b * RPB + lane);
        u64 k1 = ((u64)fkey(p1) << 32) | (u32)~(u32)(b * RPB + lane + 64);
        u64 best = (k1 > k0) ? k1 : k0;
        best = wmax64(best);
        if (lane == 0) publish(&part[b], best);   // part[0*NBLK + b]
    }
    asm volatile("" ::: "memory");   // keep the publishes before the E stream

    // ---- Phase B: stream E rows into registers + normalize (hides A) ----
    const int row0 = b * RPB + wv * RPW;
    float r[RPW][8];
#pragma unroll
    for (int rr = 0; rr < RPW; ++rr) {
        const float4* p = (const float4*)(E + (size_t)(row0 + rr) * D) + 2 * lane;
        float4 a0 = p[0], a1 = p[1];
        r[rr][0] = a0.x; r[rr][1] = a0.y; r[rr][2] = a0.z; r[rr][3] = a0.w;
        r[rr][4] = a1.x; r[rr][5] = a1.y; r[rr][6] = a1.z; r[rr][7] = a1.w;
        float ss = 0.f;
#pragma unroll
        for (int e = 0; e < 8; ++e) ss += r[rr][e] * r[rr][e];
        ss = wsum(ss);
        float inv = 1.f / (sqrtf(ss) + EPSF);
#pragma unroll
        for (int e = 0; e < 8; ++e) r[rr][e] *= inv;
        asm volatile("" : "+v"(r[rr][0]), "+v"(r[rr][1]), "+v"(r[rr][2]), "+v"(r[rr][3]),
                          "+v"(r[rr][4]), "+v"(r[rr][5]), "+v"(r[rr][6]), "+v"(r[rr][7]));
    }

    // ---- Phase C: combine softmax partials (slots long-visible by now) ----
    if (tid < NBLK) scan_s[tid] = poll_sleep(&sm[tid]);
    __syncthreads();
    if (wv == 0) {
        u64 v0 = scan_s[lane], v1 = scan_s[lane + 64],
            v2 = scan_s[lane + 128], v3 = scan_s[lane + 192];
        float m0 = __uint_as_float((u32)(v0 >> 32)), m1 = __uint_as_float((u32)(v1 >> 32));
        float m2 = __uint_as_float((u32)(v2 >> 32)), m3 = __uint_as_float((u32)(v3 >> 32));
        float M = wmaxf(fmaxf(fmaxf(m0, m1), fmaxf(m2, m3)));   // wave-uniform
        float acc = __uint_as_float((u32)(v0 & 0xFFFFFFFFull)) * expf(m0 - M)
                  + __uint_as_float((u32)(v1 & 0xFFFFFFFFull)) * expf(m1 - M)
                  + __uint_as_float((u32)(v2 & 0xFFFFFFFFull)) * expf(m2 - M)
                  + __uint_as_float((u32)(v3 & 0xFFFFFFFFull)) * expf(m3 - M);
        acc = wsum(acc);
        if (lane == 0) { m_s = M; S_s = acc; }
    }
    __syncthreads();
    const float M    = m_s;
    const float Sinv = 1.f / S_s;

    // per-wave private state (wave-uniform, registers). drel = decay^t * rel.
    float drel_r[RPW], msim_r[RPW];
#pragma unroll
    for (int rr = 0; rr < RPW; ++rr) {
        drel_r[rr] = expf(pred_s[wv * RPW + rr] - M) * Sinv;
        msim_r[rr] = 0.f;
    }

    // ---- greedy selection: round 0 pre-published; 2 barriers/round ----
    int j = -1;
    for (int t = 0; t < KMAX; ++t) {
        if (t >= kk) break;                       // uniform across grid
        if (t > 0) {
            // fused: load+normalize E_j, update msim, mask selected row
            const float4* pj = (const float4*)(E + (size_t)j * D) + 2 * lane;
            float4 b0 = pj[0], b1 = pj[1];
            float bj[8] = {b0.x, b0.y, b0.z, b0.w, b1.x, b1.y, b1.z, b1.w};
            float ss = 0.f;
#pragma unroll
            for (int e = 0; e < 8; ++e) ss += bj[e] * bj[e];
            ss = wsum(ss);
            const float js = 1.f / (sqrtf(ss) + EPSF);
#pragma unroll
            for (int e = 0; e < 8; ++e) bj[e] *= js;
#pragma unroll
            for (int rr = 0; rr < RPW; ++rr) {
                float d = 0.f;
#pragma unroll
                for (int e = 0; e < 8; ++e) d += r[rr][e] * bj[e];
                d = wsum(d);
                msim_r[rr] = (row0 + rr == j) ? INFINITY
                                              : fmaxf(msim_r[rr], d);
            }
            // wave-local best key (values wave-uniform)
            u64 best = 0ull;
#pragma unroll
            for (int rr = 0; rr < RPW; ++rr) {
                const float sc = drel_r[rr] - LAMF * msim_r[rr];
                const u64 key = ((u64)fkey(sc) << 32) | (u32)~(u32)(row0 + rr);
                best = (key > best) ? key : best;
            }
            if (lane == 0) wkey_s[wv] = best;
            __syncthreads();                                   // B1
            if (wv == 0) {
                u64 v = (lane < NW) ? wkey_s[lane] : 0ull;
                v = wmax64(v);
                if (lane == 0) publish(&part[(size_t)t * NBLK + b], v);
            }
        }
#pragma unroll
        for (int rr = 0; rr < RPW; ++rr) drel_r[rr] *= DECAYF;  // decay^(t+1)
        if (wv == 0) {
            u64* base = part + (size_t)t * NBLK;
            u64* bc   = bcast + (size_t)t * BREP * BSTR;
            if (b == 0) {
                // leader: interleaved non-blocking tight poll, 4 slots/lane
                u64 a0 = 0, a1 = 0, a2 = 0, a3 = 0;
                for (;;) {
                    if (a0 == 0ull) a0 = aload(&base[lane]);
                    if (a1 == 0ull) a1 = aload(&base[lane + 64]);
                    if (a2 == 0ull) a2 = aload(&base[lane + 128]);
                    if (a3 == 0ull) a3 = aload(&base[lane + 192]);
                    if (a0 && a1 && a2 && a3) break;
                }
                u64 m = (a1 > a0) ? a1 : a0;
                m = (a2 > m) ? a2 : m;
                m = (a3 > m) ? a3 : m;
                m = wmax64(m);                     // max in ALL lanes
                if (lane < BREP) publish(&bc[lane * BSTR], m);  // 8 replicas
            }
            if (lane == 0) {
                const u64 m = poll_tight(&bc[(b >> 5) * BSTR]);
                const int jj = (int)~(u32)(m & 0xFFFFFFFFull);
                j_s = jj;
                sel_s[t] = jj;
            }
        }
        __syncthreads();                                       // B2
        j = j_s;
    }

    // ---- epilogue (block 0 only) ----
    if (b == 0) {
        for (int ii = wv; ii < kk; ii += NW) {
            const int si = sel_s[ii];
            const float4* pa = (const float4*)(E + (size_t)si * D) + 2 * lane;
            float4 a0 = pa[0], a1 = pa[1];
            float ss = a0.x*a0.x + a0.y*a0.y + a0.z*a0.z + a0.w*a0.w
                     + a1.x*a1.x + a1.y*a1.y + a1.z*a1.z + a1.w*a1.w;
            ss = wsum(ss);
            if (lane == 0) invsel_s[ii] = 1.f / (sqrtf(ss) + EPSF);
        }
        __syncthreads();
        for (int ii = wv; ii < kk; ii += NW) {
            const int si = sel_s[ii];
            const float4* pa = (const float4*)(E + (size_t)si * D) + 2 * lane;
            float4 a0 = pa[0], a1 = pa[1];
            const float ia = invsel_s[ii];
            float av[8] = {a0.x * ia, a0.y * ia, a0.z * ia, a0.w * ia,
                           a1.x * ia, a1.y * ia, a1.z * ia, a1.w * ia};
            float m = -INFINITY;
            for (int jj = 0; jj < kk; ++jj) {
                const float4* pb = (const float4*)(E + (size_t)sel_s[jj] * D) + 2 * lane;
                float4 c0 = pb[0], c1 = pb[1];
                float d = av[0]*c0.x + av[1]*c0.y + av[2]*c0.z + av[3]*c0.w
                        + av[4]*c1.x + av[5]*c1.y + av[6]*c1.z + av[7]*c1.w;
                d = wsum(d);
                m = fmaxf(m, d * invsel_s[jj]);
            }
            if (lane == 0) rmax_s[ii] = m;
        }
        __syncthreads();
        if (tid == 0) {
            float es = 0.f, mm = 0.f;
            for (int t = 0; t < kk; ++t) {
                es += powf(DECAYF, (float)t) * expf(pred[sel_s[t]] - M) * Sinv;
                mm += rmax_s[t];
            }
            out[0] = -es - LAMF * mm;
        }
    }
}

extern "C" void kernel_launch(void* const* d_in, const int* in_sizes, int n_in,
                              void* d_out, int out_size, void* d_ws, size_t ws_size,
                              hipStream_t stream) {
    const float* pred = (const float*)d_in[0];
    const float* E    = (const float*)d_in[5];
    const int*   kptr = (const int*)d_in[6];
    float* out        = (float*)d_out;

    // workspace: sm[256] + part[16][256] + bcast[16][8*16], u64.
    // Zeroed each launch so poll sentinels (0) are fresh per graph replay.
    u64* sm    = (u64*)d_ws;
    u64* part  = sm + NBLK;
    u64* bcast = part + (size_t)KMAX * NBLK;
    const size_t tot = NBLK + (size_t)KMAX * NBLK + (size_t)KMAX * BREP * BSTR;
    hipMemsetAsync(d_ws, 0, tot * sizeof(u64), stream);

    void* args[] = {(void*)&pred, (void*)&E, (void*)&kptr, (void*)&out,
                    (void*)&sm, (void*)&part, (void*)&bcast};
    hipLaunchCooperativeKernel((const void*)fused_kernel,
                               dim3(NBLK), dim3(TPB), args, 0, stream);
}